// Round 9
// baseline (134.586 us; speedup 1.0000x reference)
//
#include <hip/hip_runtime.h>
#include <hip/hip_bf16.h>

typedef short s4 __attribute__((ext_vector_type(4)));
typedef short s8 __attribute__((ext_vector_type(8)));
typedef float f4 __attribute__((ext_vector_type(4)));

#define MFMA16(a, b, c) __builtin_amdgcn_mfma_f32_16x16x16bf16_1k(a, b, c, 0, 0, 0)

__device__ __forceinline__ short f2bf(float f) {
    union { float f; unsigned u; } v; v.f = f;
    unsigned r = v.u + 0x7fffu + ((v.u >> 16) & 1u);   // RNE
    return (short)(r >> 16);
}

// ---------------------------------------------------------------------------
// Kernel 1: projections — identical to round 8 (best timed performer).
// ---------------------------------------------------------------------------
struct ProjArgs {
    const float* X[3];
    const float* W[3];
    const float* b[3];
    unsigned short* O[3];
};

__global__ __launch_bounds__(256) void proj_kernel(ProjArgs args) {
    __shared__ short lA[64][68];   // [row][k]
    __shared__ short lW[64][68];   // [k][n]

    const int t  = threadIdx.x;
    const int wv = t >> 6, ln = t & 63, lg = ln >> 4, lr = ln & 15;
    const int which = blockIdx.y;

    const float* X = args.X[which] + (size_t)blockIdx.x * 64 * 1024;
    const float* W = args.W[which];

    f4 acc[4] = {f4{0,0,0,0}, f4{0,0,0,0}, f4{0,0,0,0}, f4{0,0,0,0}};

    for (int kk = 0; kk < 1024; kk += 64) {
        #pragma unroll
        for (int i = 0; i < 4; ++i) {
            int f  = t + i * 256;       // float4 index, 0..1023
            int r  = f >> 4;
            int c4 = f & 15;
            f4 a = *(const f4*)(X + (size_t)r * 1024 + kk + c4 * 4);
            f4 w = *(const f4*)(W + (size_t)(kk + r) * 64 + c4 * 4);
            s4 ab; ab[0]=f2bf(a[0]); ab[1]=f2bf(a[1]); ab[2]=f2bf(a[2]); ab[3]=f2bf(a[3]);
            s4 wb; wb[0]=f2bf(w[0]); wb[1]=f2bf(w[1]); wb[2]=f2bf(w[2]); wb[3]=f2bf(w[3]);
            *(s4*)&lA[r][c4 * 4] = ab;
            *(s4*)&lW[r][c4 * 4] = wb;
        }
        __syncthreads();

        #pragma unroll
        for (int ks = 0; ks < 4; ++ks) {
            s4 af = *(const s4*)&lA[wv * 16 + lr][ks * 16 + 4 * lg];
            #pragma unroll
            for (int nf = 0; nf < 4; ++nf) {
                s4 bf;
                #pragma unroll
                for (int e = 0; e < 4; ++e)
                    bf[e] = lW[ks * 16 + 4 * lg + e][nf * 16 + lr];
                acc[nf] = MFMA16(af, bf, acc[nf]);
            }
        }
        __syncthreads();
    }

    // epilogue: + bias, bf16, store (V transposed per 64-key tile)
    const float* bias = args.b[which];
    unsigned short* O = args.O[which];
    #pragma unroll
    for (int nf = 0; nf < 4; ++nf) {
        float bs = bias[nf * 16 + lr];
        int col = nf * 16 + lr;
        #pragma unroll
        for (int e = 0; e < 4; ++e) {
            int r = wv * 16 + 4 * lg + e;
            int grow = blockIdx.x * 64 + r;
            unsigned short val = (unsigned short)f2bf(acc[nf][e] + bs);
            if (which == 2) {
                size_t idx = (size_t)(grow >> 11) * 131072
                           + (size_t)((grow & 2047) >> 6) * 4096
                           + (size_t)col * 64 + (grow & 63);
                O[idx] = val;
            } else {
                O[(size_t)grow * 64 + col] = val;
            }
        }
    }
}

// ---------------------------------------------------------------------------
// Kernel 2: causal flash attention — identical to round 8.
// LAUNCHED 3x THIS ROUND (idempotent) to measure attn's timed-regime cost:
// attn_timed = (R9_total - R8_total) / 2.
// ---------------------------------------------------------------------------
__global__ __launch_bounds__(512) void attn_kernel(const unsigned short* __restrict__ qp,
                                                   const unsigned short* __restrict__ kp,
                                                   const unsigned short* __restrict__ vpT,
                                                   float* __restrict__ out) {
    __shared__ short lK[2][2][64][72];   // [half][buf][key][d]
    __shared__ short lV[2][2][64][72];   // [half][buf][d][key]

    const int t    = threadIdx.x;
    const int wave = t >> 6, ln = t & 63, lg = ln >> 4, lr = ln & 15;
    const int half = wave >> 2, hw = wave & 3;
    const int b = blockIdx.y, qt = blockIdx.x;
    const int qrow = qt * 64 + hw * 16 + lr;
    const int h = (qt + 2) >> 1;

    // staging role: 128-thread groups g: 0=K half0, 1=V half0, 2=K half1, 3=V half1
    const int g = t >> 7, gi = t & 127, ghalf = g >> 1;
    const bool isV = (g & 1) != 0;
    const unsigned short* tb = (isV ? vpT : kp) + (size_t)b * 131072;

    const unsigned short* qpb = qp + (size_t)b * 131072;
    s4 qf[4];
    #pragma unroll
    for (int ks = 0; ks < 4; ++ks)
        qf[ks] = *(const s4*)(qpb + (size_t)qrow * 64 + ks * 16 + 4 * lg);

    f4 accO[4] = {f4{0,0,0,0}, f4{0,0,0,0}, f4{0,0,0,0}, f4{0,0,0,0}};
    float m = -3e38f, lsum = 0.f;

    // prologue: prefetch iter-0 tile for this thread's (tensor, half)
    s8 stg[4];
    {
        const unsigned short* p = tb + (size_t)(ghalf ? h : 0) * 4096;
        #pragma unroll
        for (int i = 0; i < 4; ++i)
            stg[i] = *(const s8*)(p + (gi + 128 * i) * 8);
    }

    int buf = 0;
    for (int j = 0; j < h; ++j) {
        // write staged regs -> LDS[ghalf][buf]; K and V use identical layout
        {
            short (*dst)[72] = isV ? lV[ghalf][buf] : lK[ghalf][buf];
            #pragma unroll
            for (int i = 0; i < 4; ++i) {
                int s = gi + 128 * i;
                *(s8*)&dst[s >> 3][(s & 7) * 8] = stg[i];
            }
        }
        __syncthreads();

        // prefetch next tile (hides under compute below)
        if (j + 1 < h) {
            const unsigned short* p = tb + (size_t)((ghalf ? h : 0) + j + 1) * 4096;
            #pragma unroll
            for (int i = 0; i < 4; ++i)
                stg[i] = *(const s8*)(p + (gi + 128 * i) * 8);
        }

        const int kt = (half ? h : 0) + j;
        if (kt <= qt) {                      // half-B pad iter skips
            // S^T = K . Q^T
            f4 st[4];
            #pragma unroll
            for (int kf = 0; kf < 4; ++kf) {
                f4 a = f4{0,0,0,0};
                #pragma unroll
                for (int ks = 0; ks < 4; ++ks) {
                    s4 kfr = *(const s4*)&lK[half][buf][kf * 16 + lr][ks * 16 + 4 * lg];
                    a = MFMA16(kfr, qf[ks], a);
                }
                st[kf] = a;
            }

            const bool diag = (kt == qt);
            const int kbase = kt * 64;
            float smax = -3e38f;
            #pragma unroll
            for (int kf = 0; kf < 4; ++kf) {
                #pragma unroll
                for (int e = 0; e < 4; ++e) {
                    float s = st[kf][e] * 0.125f;
                    if (diag && (kbase + kf * 16 + 4 * lg + e > qrow)) s = -3e38f;
                    st[kf][e] = s;
                    smax = fmaxf(smax, s);
                }
            }
            smax = fmaxf(smax, __shfl_xor(smax, 16));
            smax = fmaxf(smax, __shfl_xor(smax, 32));

            float mnew  = fmaxf(m, smax);
            float scale = __expf(m - mnew);
            float psum  = 0.f;
            s4 pf[4];
            #pragma unroll
            for (int kf = 0; kf < 4; ++kf) {
                f4 p;
                #pragma unroll
                for (int e = 0; e < 4; ++e) { p[e] = __expf(st[kf][e] - mnew); psum += p[e]; }
                s4 pb; pb[0]=f2bf(p[0]); pb[1]=f2bf(p[1]); pb[2]=f2bf(p[2]); pb[3]=f2bf(p[3]);
                pf[kf] = pb;
            }
            psum += __shfl_xor(psum, 16);
            psum += __shfl_xor(psum, 32);
            lsum = lsum * scale + psum;
            m = mnew;
            #pragma unroll
            for (int df = 0; df < 4; ++df) accO[df] *= scale;

            #pragma unroll
            for (int df = 0; df < 4; ++df) {
                #pragma unroll
                for (int kf = 0; kf < 4; ++kf) {
                    s4 vf = *(const s4*)&lV[half][buf][df * 16 + lr][kf * 16 + 4 * lg];
                    accO[df] = MFMA16(vf, pf[kf], accO[df]);
                }
            }
        }
        buf ^= 1;
    }

    // ---- merge halves: B publishes (m, l, accO) via LDS; A combines ----
    __syncthreads();
    float* ex = (float*)&lK[0][0][0][0];     // 256*19 floats = 19.4 KB, fits
    const int idx = (hw * 64 + ln) * 19;
    if (half == 1) {
        ex[idx + 0] = m;
        ex[idx + 1] = lsum;
        #pragma unroll
        for (int df = 0; df < 4; ++df)
            #pragma unroll
            for (int e = 0; e < 4; ++e)
                ex[idx + 2 + df * 4 + e] = accO[df][e];
    }
    __syncthreads();
    if (half == 0) {
        float mB = ex[idx + 0], lB = ex[idx + 1];
        float mx = fmaxf(m, mB);
        float sA = __expf(m - mx), sB = __expf(mB - mx);
        float linv = 1.f / (lsum * sA + lB * sB);
        float* ob = out + ((size_t)b * 2048 + qrow) * 64;
        #pragma unroll
        for (int df = 0; df < 4; ++df) {
            f4 o;
            #pragma unroll
            for (int e = 0; e < 4; ++e)
                o[e] = (accO[df][e] * sA + ex[idx + 2 + df * 4 + e] * sB) * linv;
            *(f4*)(ob + df * 16 + 4 * lg) = o;
        }
    }
}

// ---------------------------------------------------------------------------
extern "C" void kernel_launch(void* const* d_in, const int* in_sizes, int n_in,
                              void* d_out, int out_size, void* d_ws, size_t ws_size,
                              hipStream_t stream) {
    const float* q  = (const float*)d_in[0];
    const float* k  = (const float*)d_in[1];
    const float* v  = (const float*)d_in[2];
    // d_in[3] = causal mask (deterministic tril) — computed analytically
    const float* Wq = (const float*)d_in[4];
    const float* bq = (const float*)d_in[5];
    const float* Wk = (const float*)d_in[6];
    const float* bk = (const float*)d_in[7];
    const float* Wv = (const float*)d_in[8];
    const float* bv = (const float*)d_in[9];

    unsigned short* qp  = (unsigned short*)d_ws;           // [16384][64] bf16
    unsigned short* kp  = qp + (size_t)16384 * 64;
    unsigned short* vpT = kp + (size_t)16384 * 64;         // V^T tiles [b][t][d][key]

    ProjArgs pa;
    pa.X[0] = q;  pa.X[1] = k;  pa.X[2] = v;
    pa.W[0] = Wq; pa.W[1] = Wk; pa.W[2] = Wv;
    pa.b[0] = bq; pa.b[1] = bk; pa.b[2] = bv;
    pa.O[0] = qp; pa.O[1] = kp; pa.O[2] = vpT;
    proj_kernel<<<dim3(256, 3), 256, 0, stream>>>(pa);

    // Measurement round: attn launched 3x (idempotent) to expose its
    // timed-regime cost: attn = (total_R9 - total_R8) / 2.
    attn_kernel<<<dim3(32, 8), 512, 0, stream>>>(qp, kp, vpT, (float*)d_out);
    attn_kernel<<<dim3(32, 8), 512, 0, stream>>>(qp, kp, vpT, (float*)d_out);
    attn_kernel<<<dim3(32, 8), 512, 0, stream>>>(qp, kp, vpT, (float*)d_out);
}

// Round 10
// 81.547 us; speedup vs baseline: 1.6504x; 1.6504x over previous
//
#include <hip/hip_runtime.h>
#include <hip/hip_bf16.h>

typedef short s4 __attribute__((ext_vector_type(4)));
typedef short s8 __attribute__((ext_vector_type(8)));
typedef float f4 __attribute__((ext_vector_type(4)));

#define MFMA16(a, b, c) __builtin_amdgcn_mfma_f32_16x16x16bf16_1k(a, b, c, 0, 0, 0)

__device__ __forceinline__ short f2bf(float f) {
    union { float f; unsigned u; } v; v.f = f;
    unsigned r = v.u + 0x7fffu + ((v.u >> 16) & 1u);   // RNE
    return (short)(r >> 16);
}

// ---------------------------------------------------------------------------
// Kernel 1: projections — identical to round 8 (timed ~47 us warm; cold
// rocprof ~86 us is the serialized-cold regime, not what the harness times).
// ---------------------------------------------------------------------------
struct ProjArgs {
    const float* X[3];
    const float* W[3];
    const float* b[3];
    unsigned short* O[3];
};

__global__ __launch_bounds__(256) void proj_kernel(ProjArgs args) {
    __shared__ short lA[64][68];   // [row][k]
    __shared__ short lW[64][68];   // [k][n]

    const int t  = threadIdx.x;
    const int wv = t >> 6, ln = t & 63, lg = ln >> 4, lr = ln & 15;
    const int which = blockIdx.y;

    const float* X = args.X[which] + (size_t)blockIdx.x * 64 * 1024;
    const float* W = args.W[which];

    f4 acc[4] = {f4{0,0,0,0}, f4{0,0,0,0}, f4{0,0,0,0}, f4{0,0,0,0}};

    for (int kk = 0; kk < 1024; kk += 64) {
        #pragma unroll
        for (int i = 0; i < 4; ++i) {
            int f  = t + i * 256;       // float4 index, 0..1023
            int r  = f >> 4;
            int c4 = f & 15;
            f4 a = *(const f4*)(X + (size_t)r * 1024 + kk + c4 * 4);
            f4 w = *(const f4*)(W + (size_t)(kk + r) * 64 + c4 * 4);
            s4 ab; ab[0]=f2bf(a[0]); ab[1]=f2bf(a[1]); ab[2]=f2bf(a[2]); ab[3]=f2bf(a[3]);
            s4 wb; wb[0]=f2bf(w[0]); wb[1]=f2bf(w[1]); wb[2]=f2bf(w[2]); wb[3]=f2bf(w[3]);
            *(s4*)&lA[r][c4 * 4] = ab;
            *(s4*)&lW[r][c4 * 4] = wb;
        }
        __syncthreads();

        #pragma unroll
        for (int ks = 0; ks < 4; ++ks) {
            s4 af = *(const s4*)&lA[wv * 16 + lr][ks * 16 + 4 * lg];
            #pragma unroll
            for (int nf = 0; nf < 4; ++nf) {
                s4 bf;
                #pragma unroll
                for (int e = 0; e < 4; ++e)
                    bf[e] = lW[ks * 16 + 4 * lg + e][nf * 16 + lr];
                acc[nf] = MFMA16(af, bf, acc[nf]);
            }
        }
        __syncthreads();
    }

    // epilogue: + bias, bf16, store (V transposed per 64-key tile)
    const float* bias = args.b[which];
    unsigned short* O = args.O[which];
    #pragma unroll
    for (int nf = 0; nf < 4; ++nf) {
        float bs = bias[nf * 16 + lr];
        int col = nf * 16 + lr;
        #pragma unroll
        for (int e = 0; e < 4; ++e) {
            int r = wv * 16 + 4 * lg + e;
            int grow = blockIdx.x * 64 + r;
            unsigned short val = (unsigned short)f2bf(acc[nf][e] + bs);
            if (which == 2) {
                size_t idx = (size_t)(grow >> 11) * 131072
                           + (size_t)((grow & 2047) >> 6) * 4096
                           + (size_t)col * 64 + (grow & 63);
                O[idx] = val;
            } else {
                O[(size_t)grow * 64 + col] = val;
            }
        }
    }
}

// ---------------------------------------------------------------------------
// Kernel 2 v10: causal flash attention, 2 blocks/CU for cross-block overlap.
// q-tile = 32 rows, block = 4 waves (2 q-strips x 2 kv-halves).
// grid (64, 8) = 512 blocks -> 2 co-resident blocks/CU (LDS 74 KB).
// Staging: wave w stages (tensor = w&1 ? V : K, half = w>>1): 8 x s8/thread.
// Double-buffered LDS, ONE barrier/iter, reg prefetch (v8-proven pattern).
// kv prefix P = g/2+1 tiles; half0 = [0,h), half1 = [h,P), h = ceil(P/2).
// ---------------------------------------------------------------------------
__global__ __launch_bounds__(256) void attn_kernel(const unsigned short* __restrict__ qp,
                                                   const unsigned short* __restrict__ kp,
                                                   const unsigned short* __restrict__ vpT,
                                                   float* __restrict__ out) {
    __shared__ short lK[2][2][64][72];   // [half][buf][key][d]
    __shared__ short lV[2][2][64][72];   // [half][buf][d][key]

    const int t    = threadIdx.x;
    const int wave = t >> 6, ln = t & 63, lg = ln >> 4, lr = ln & 15;
    const int strip = wave >> 1, half = wave & 1;       // compute roles
    const int b = blockIdx.y, g = blockIdx.x;           // 32-row q-tile index
    const int qrow = g * 32 + strip * 16 + lr;
    const int P = (g >> 1) + 1;                         // kv-prefix tiles
    const int h = (P + 1) >> 1;

    // staging role: wave w stages (half = w>>1, tensor = w&1 ? V : K)
    const int sHalf = wave >> 1;
    const bool sIsV = (wave & 1) != 0;
    const unsigned short* tb = (sIsV ? vpT : kp) + (size_t)b * 131072;

    const unsigned short* qpb = qp + (size_t)b * 131072;
    s4 qf[4];
    #pragma unroll
    for (int ks = 0; ks < 4; ++ks)
        qf[ks] = *(const s4*)(qpb + (size_t)qrow * 64 + ks * 16 + 4 * lg);

    f4 accO[4] = {f4{0,0,0,0}, f4{0,0,0,0}, f4{0,0,0,0}, f4{0,0,0,0}};
    float m = -3e38f, lsum = 0.f;

    // prologue: prefetch iter-0 tile (64x64 bf16 = 512 s8, 8 per thread)
    s8 stg[8];
    {
        const unsigned short* p = tb + (size_t)(sHalf ? h : 0) * 4096;
        #pragma unroll
        for (int i = 0; i < 8; ++i)
            stg[i] = *(const s8*)(p + (ln + 64 * i) * 8);
    }

    int buf = 0;
    for (int j = 0; j < h; ++j) {
        // write staged regs -> LDS[sHalf][buf]
        {
            short (*dst)[72] = sIsV ? lV[sHalf][buf] : lK[sHalf][buf];
            #pragma unroll
            for (int i = 0; i < 8; ++i) {
                int s = ln + 64 * i;
                *(s8*)&dst[s >> 3][(s & 7) * 8] = stg[i];
            }
        }
        __syncthreads();

        // prefetch next tile (hides under compute below)
        if (j + 1 < h) {
            const unsigned short* p = tb + (size_t)((sHalf ? h : 0) + j + 1) * 4096;
            #pragma unroll
            for (int i = 0; i < 8; ++i)
                stg[i] = *(const s8*)(p + (ln + 64 * i) * 8);
        }

        const int kt = (half ? h : 0) + j;
        if (kt < P) {                        // half1 pad iter skips
            // S^T = K . Q^T
            f4 st[4];
            #pragma unroll
            for (int kf = 0; kf < 4; ++kf) {
                f4 a = f4{0,0,0,0};
                #pragma unroll
                for (int ks = 0; ks < 4; ++ks) {
                    s4 kfr = *(const s4*)&lK[half][buf][kf * 16 + lr][ks * 16 + 4 * lg];
                    a = MFMA16(kfr, qf[ks], a);
                }
                st[kf] = a;
            }

            const bool diag = (kt == P - 1);
            const int kbase = kt * 64;
            float smax = -3e38f;
            #pragma unroll
            for (int kf = 0; kf < 4; ++kf) {
                #pragma unroll
                for (int e = 0; e < 4; ++e) {
                    float s = st[kf][e] * 0.125f;
                    if (diag && (kbase + kf * 16 + 4 * lg + e > qrow)) s = -3e38f;
                    st[kf][e] = s;
                    smax = fmaxf(smax, s);
                }
            }
            smax = fmaxf(smax, __shfl_xor(smax, 16));
            smax = fmaxf(smax, __shfl_xor(smax, 32));

            float mnew  = fmaxf(m, smax);
            float scale = __expf(m - mnew);
            float psum  = 0.f;
            s4 pf[4];
            #pragma unroll
            for (int kf = 0; kf < 4; ++kf) {
                f4 p;
                #pragma unroll
                for (int e = 0; e < 4; ++e) { p[e] = __expf(st[kf][e] - mnew); psum += p[e]; }
                s4 pb; pb[0]=f2bf(p[0]); pb[1]=f2bf(p[1]); pb[2]=f2bf(p[2]); pb[3]=f2bf(p[3]);
                pf[kf] = pb;
            }
            psum += __shfl_xor(psum, 16);
            psum += __shfl_xor(psum, 32);
            lsum = lsum * scale + psum;
            m = mnew;
            #pragma unroll
            for (int df = 0; df < 4; ++df) accO[df] *= scale;

            #pragma unroll
            for (int df = 0; df < 4; ++df) {
                #pragma unroll
                for (int kf = 0; kf < 4; ++kf) {
                    s4 vf = *(const s4*)&lV[half][buf][df * 16 + lr][kf * 16 + 4 * lg];
                    accO[df] = MFMA16(vf, pf[kf], accO[df]);
                }
            }
        }
        buf ^= 1;
    }

    // ---- merge halves per strip: half1 publishes, half0 combines ----
    __syncthreads();
    float* ex = (float*)&lK[0][0][0][0];     // 2*64*18 floats = 9.2 KB, fits
    const int idx = (strip * 64 + ln) * 18;
    if (half == 1) {
        ex[idx + 0] = m;
        ex[idx + 1] = lsum;
        #pragma unroll
        for (int df = 0; df < 4; ++df)
            #pragma unroll
            for (int e = 0; e < 4; ++e)
                ex[idx + 2 + df * 4 + e] = accO[df][e];
    }
    __syncthreads();
    if (half == 0) {
        float mB = ex[idx + 0], lB = ex[idx + 1];
        float mx = fmaxf(m, mB);
        float sA = __expf(m - mx), sB = __expf(mB - mx);
        float linv = 1.f / (lsum * sA + lB * sB);
        float* ob = out + ((size_t)b * 2048 + qrow) * 64;
        #pragma unroll
        for (int df = 0; df < 4; ++df) {
            f4 o;
            #pragma unroll
            for (int e = 0; e < 4; ++e)
                o[e] = (accO[df][e] * sA + ex[idx + 2 + df * 4 + e] * sB) * linv;
            *(f4*)(ob + df * 16 + 4 * lg) = o;
        }
    }
}

// ---------------------------------------------------------------------------
extern "C" void kernel_launch(void* const* d_in, const int* in_sizes, int n_in,
                              void* d_out, int out_size, void* d_ws, size_t ws_size,
                              hipStream_t stream) {
    const float* q  = (const float*)d_in[0];
    const float* k  = (const float*)d_in[1];
    const float* v  = (const float*)d_in[2];
    // d_in[3] = causal mask (deterministic tril) — computed analytically
    const float* Wq = (const float*)d_in[4];
    const float* bq = (const float*)d_in[5];
    const float* Wk = (const float*)d_in[6];
    const float* bk = (const float*)d_in[7];
    const float* Wv = (const float*)d_in[8];
    const float* bv = (const float*)d_in[9];

    unsigned short* qp  = (unsigned short*)d_ws;           // [16384][64] bf16
    unsigned short* kp  = qp + (size_t)16384 * 64;
    unsigned short* vpT = kp + (size_t)16384 * 64;         // V^T tiles [b][t][d][key]

    ProjArgs pa;
    pa.X[0] = q;  pa.X[1] = k;  pa.X[2] = v;
    pa.W[0] = Wq; pa.W[1] = Wk; pa.W[2] = Wv;
    pa.b[0] = bq; pa.b[1] = bk; pa.b[2] = bv;
    pa.O[0] = qp; pa.O[1] = kp; pa.O[2] = vpT;
    proj_kernel<<<dim3(256, 3), 256, 0, stream>>>(pa);

    attn_kernel<<<dim3(64, 8), 256, 0, stream>>>(qp, kp, vpT, (float*)d_out);
}